// Round 7
// baseline (158.727 us; speedup 1.0000x reference)
//
#include <hip/hip_runtime.h>
#include <math.h>

#define NH 8
#define BITS_ 5
#define NB 40
#define TS 64
#define MAUG 27
#define CIN 64
#define HH 56
#define WW 56
#define NN 32
#define OCH 256
#define DK 576
#define DPM 603
#define HW (HH*WW)

#define CP64 36            // dwords per (r,L) cell: 32 data (64ch x f16) + 4 pad
#define TILE1 7344         // 3 rows * 68 cols * CP64 (dwords) per precision tile

typedef __attribute__((ext_vector_type(4))) float f32x4;
typedef __attribute__((ext_vector_type(8))) _Float16 f16x8;
typedef union { uint4 u; f16x8 h; } fragh_u;

__device__ __forceinline__ unsigned int f16b(float v) {
    union { _Float16 h; unsigned short u; } cv;
    cv.h = (_Float16)v;
    return (unsigned int)cv.u;
}
__device__ __forceinline__ float f16tof(unsigned int b) {
    union { _Float16 h; unsigned short u; } cv;
    cv.u = (unsigned short)b;
    return (float)cv.h;
}

// ---------------- kP: all prep (aT, ctab, zero tallied, norm partials, weight pack) ----
__global__ void kP(const float* __restrict__ kern, const float* __restrict__ a,
                   float* __restrict__ aT, float* __restrict__ ctab,
                   int* __restrict__ tallied, float* __restrict__ normP,
                   unsigned short* __restrict__ whA,
                   unsigned short* __restrict__ vaH, unsigned short* __restrict__ vaL)
{
    const int bid = blockIdx.x;
    const int t = threadIdx.x;
    if (bid < 32) {                       // transpose a -> aT
        for (int idx = bid * 256 + t; idx < DPM * NB; idx += 32 * 256) {
            int d = idx / NB, j = idx - d * NB;
            aT[idx] = a[j * DPM + d];
        }
    } else if (bid == 32) {               // ctab + zero tallied
        for (int g = t; g < 9 * NB; g += 256) {
            int pat = g / NB, j = g - pat * NB;
            int ry = pat / 3, rx = pat % 3;
            float s = 0.f;
            for (int ky = 0; ky < 3; ++ky) {
                if (ry == 0 && ky == 0) continue;
                if (ry == 2 && ky == 2) continue;
                for (int kx = 0; kx < 3; ++kx) {
                    if (rx == 0 && kx == 0) continue;
                    if (rx == 2 && kx == 2) continue;
                    for (int mc = 0; mc < 3; ++mc)
                        s += a[j * DPM + DK + mc * 9 + ky * 3 + kx];
                }
            }
            ctab[g] = 0.5f * s;
        }
        for (int g = t; g < NH * TS; g += 256) tallied[g] = 0;
    } else if (bid < 37) {                // norm partials
        int g = (bid - 33) * 256 + t;     // 1024 = 256 oc * 4 parts
        int oc = g >> 2, part = g & 3;
        const float4* p = (const float4*)(kern + oc * DK + part * 144);
        float sq = 0.f;
        #pragma unroll 4
        for (int i = 0; i < 36; ++i) {
            float4 v = p[i];
            sq += v.x * v.x + v.y * v.y + v.z * v.z + v.w * v.w;
        }
        normP[g] = sq;
    } else {                              // weight packing (342 frags * 64 lanes)
        int idx = (bid - 37) * 256 + t;
        int f = idx >> 6, lane = idx & 63;
        if (f < 288) {                    // main conv: single f16 A-frags
            const int kidxG = f >> 4, mf = f & 15;
            const int tap = kidxG % 9, cc = kidxG / 9;
            const int oc = mf * 16 + (lane & 15);
            const int cbase = cc * 32 + (lane >> 4) * 8;
            unsigned int hs[8];
            #pragma unroll
            for (int j = 0; j < 8; ++j)
                hs[j] = f16b(kern[oc * DK + (cbase + j) * 9 + tap]);
            unsigned int* p = (unsigned int*)(whA + ((size_t)f * 64 + lane) * 8);
            #pragma unroll
            for (int w2 = 0; w2 < 4; ++w2)
                p[w2] = hs[2 * w2] | (hs[2 * w2 + 1] << 16);
        } else if (f < 342) {             // vote: f16 hi/lo A-frags
            const int fv = f - 288;
            const int kidxG = fv / 3, mfv = fv % 3;
            const int tap = kidxG % 9, cc = kidxG / 9;
            const int j = mfv * 16 + (lane & 15);
            const int cbase = cc * 32 + (lane >> 4) * 8;
            unsigned int hs[8], ls[8];
            #pragma unroll
            for (int jj = 0; jj < 8; ++jj) {
                float w = (j < NB) ? a[j * DPM + (cbase + jj) * 9 + tap] : 0.f;
                unsigned int h = f16b(w);
                unsigned int l = f16b(w - f16tof(h));
                hs[jj] = h; ls[jj] = l;
            }
            unsigned int* ph = (unsigned int*)(vaH + ((size_t)fv * 64 + lane) * 8);
            unsigned int* pl = (unsigned int*)(vaL + ((size_t)fv * 64 + lane) * 8);
            #pragma unroll
            for (int w2 = 0; w2 < 4; ++w2) {
                ph[w2] = hs[2 * w2] | (hs[2 * w2 + 1] << 16);
                pl[w2] = ls[2 * w2] | (ls[2 * w2 + 1] << 16);
            }
        }
    }
}

// ---------------- kH: hash kernel vectors, one block per oc -------------------------
__global__ void __launch_bounds__(256) kH(const float* __restrict__ kern,
        const float* __restrict__ aT, const float* __restrict__ normP,
        int* __restrict__ bucket_k)
{
    __shared__ float xs[DK];
    __shared__ float red[256];
    __shared__ float accR[3 * 41];
    __shared__ float proj[NB];
    const int t = threadIdx.x;
    const int lane = t & 63, ty = t >> 6;
    const int oc = blockIdx.x;

    red[t] = fmaxf(fmaxf(normP[t], normP[t + 256]), fmaxf(normP[t + 512], normP[t + 768]));
    __syncthreads();
    for (int s = 128; s > 0; s >>= 1) {
        if (t < s) red[t] = fmaxf(red[t], red[t + s]);
        __syncthreads();
    }
    const float scale = 0.83f / sqrtf(red[0]);
    for (int i = t; i < DK; i += 256) xs[i] = scale * kern[(size_t)oc * DK + i];
    __syncthreads();

    const int j = (lane < NB) ? lane : (NB - 1);
    float acc = 0.f, sq = 0.f;
    const int d0 = ty * 144;
    for (int d = d0; d < d0 + 144; ++d) {
        float xv = xs[d];
        sq += xv * xv;
        acc += xv * aT[d * NB + j];
    }
    if (ty > 0) {
        if (lane < NB) accR[(ty - 1) * 41 + lane] = acc;
        if (lane == NB) accR[(ty - 1) * 41 + 40] = sq;
    }
    __syncthreads();
    if (ty == 0 && lane < NB) {
        acc += (accR[lane] + accR[41 + lane]) + accR[82 + lane];
        sq += (accR[40] + accR[81]) + accR[122];
        float pv = sq;
        for (int m = 0; m < MAUG; ++m) {
            acc += pv * aT[(DK + m) * NB + lane];
            pv = pv * pv;
        }
        proj[lane] = acc;
    }
    __syncthreads();
    if (t < NH) {
        int b = 0;
        #pragma unroll
        for (int bb = 0; bb < BITS_; ++bb)
            if (proj[t * BITS_ + bb] > 0.f) b |= (1 << bb);
        bucket_k[t * OCH + oc] = b & (TS - 1);
    }
}

// ---------------- kM: single-pass 256-oc main conv + vote conv ------------------------
// grid (56, NN), block (64,8). 1 output row; 3 x-rows x 64 ch staged once (hi+lo f16).
// wave wid: oc pair (wid*2, wid*2+1); vote at nf==wid&3 (wid<4: mfv{0,1}; wid>=4: mfv{2}).
__global__ void __launch_bounds__(512) kM(const float* __restrict__ x,
        const unsigned short* __restrict__ whA,
        const unsigned short* __restrict__ vaH, const unsigned short* __restrict__ vaL,
        const float* __restrict__ ctab, int* __restrict__ tallied,
        float* __restrict__ out)
{
    __shared__ unsigned int smem[2 * TILE1];    // hi tile, lo tile
    const int lane = threadIdx.x, wid = threadIdx.y;
    const int y0 = blockIdx.x, n = blockIdx.y;
    const int lcol = lane & 15, hi4 = lane >> 4;
    const int t = wid * 64 + lane;

    f32x4 acc[2][4];
    #pragma unroll
    for (int mfl = 0; mfl < 2; ++mfl)
        #pragma unroll
        for (int nf = 0; nf < 4; ++nf)
            acc[mfl][nf] = (f32x4){0.f, 0.f, 0.f, 0.f};
    f32x4 vacc[2];
    vacc[0] = (f32x4){0.f, 0.f, 0.f, 0.f};
    vacc[1] = (f32x4){0.f, 0.f, 0.f, 0.f};
    const int vnf = wid & 3;
    const int nmf = (wid < 4) ? 2 : 1;

    if (wid >= 6) {                             // pad cells L=0 and L=65, both tiles
        int t2 = (wid - 6) * 64 + lane;
        if (t2 < 96) {
            int b = t2 & 7, rem = t2 >> 3;      // rem 0..11
            int r = rem % 3, rem2 = rem / 3;    // rem2 0..3
            int L = (rem2 & 1) ? 65 : 0, tile = rem2 >> 1;
            *(uint4*)&smem[tile * TILE1 + (r * 68 + L) * CP64 + b * 4] =
                make_uint4(0u, 0u, 0u, 0u);
        }
    } else {                                    // stage 3 rows x 64 ch, hi+lo
        const int q = lane;
        const int r = wid >> 1, half = wid & 1;
        const int y = y0 - 1 + r;
        const bool valid = (q < WW) && (y >= 0) && (y < HH);
        const float* xb = x + (((size_t)n * CIN + half * 32) * HH + (valid ? y : 0)) * WW + q;
        const int base = (r * 68 + q + 1) * CP64 + half * 16;
        #pragma unroll
        for (int u = 0; u < 4; ++u) {
            unsigned int dh[4], dl[4];
            #pragma unroll
            for (int dd = 0; dd < 4; ++dd) {
                float v0 = valid ? xb[(size_t)(u * 8 + dd * 2) * HW] : 0.f;
                float v1 = valid ? xb[(size_t)(u * 8 + dd * 2 + 1) * HW] : 0.f;
                unsigned int h0 = f16b(v0), h1 = f16b(v1);
                unsigned int l0 = f16b(v0 - f16tof(h0));
                unsigned int l1 = f16b(v1 - f16tof(h1));
                dh[dd] = h0 | (h1 << 16);
                dl[dd] = l0 | (l1 << 16);
            }
            *(uint4*)&smem[base + u * 4] = make_uint4(dh[0], dh[1], dh[2], dh[3]);
            *(uint4*)&smem[TILE1 + base + u * 4] = make_uint4(dl[0], dl[1], dl[2], dl[3]);
        }
    }
    __syncthreads();

    for (int cc = 0; cc < 2; ++cc) {
        #pragma unroll
        for (int tap = 0; tap < 9; ++tap) {
            const int ky = tap / 3, kx = tap - ky * 3;
            const int kidx = cc * 9 + tap;
            fragh_u ah0, ah1;
            ah0.u = *(const uint4*)(whA + (((size_t)kidx * 16 + wid * 2) * 64 + lane) * 8);
            ah1.u = *(const uint4*)(whA + (((size_t)kidx * 16 + wid * 2 + 1) * 64 + lane) * 8);
            #pragma unroll
            for (int nf = 0; nf < 4; ++nf) {
                const int ad = (ky * 68 + nf * 16 + lcol + kx) * CP64 + cc * 16 + hi4 * 4;
                fragh_u bh;
                bh.u = *(const uint4*)&smem[ad];
                acc[0][nf] = __builtin_amdgcn_mfma_f32_16x16x32_f16(ah0.h, bh.h, acc[0][nf], 0, 0, 0);
                acc[1][nf] = __builtin_amdgcn_mfma_f32_16x16x32_f16(ah1.h, bh.h, acc[1][nf], 0, 0, 0);
                if (nf == vnf) {
                    fragh_u bl;
                    bl.u = *(const uint4*)&smem[TILE1 + ad];
                    #pragma unroll
                    for (int ci = 0; ci < 2; ++ci) {
                        if (ci < nmf) {
                            const int mfv = (wid < 4) ? ci : 2;
                            fragh_u vh, vl;
                            size_t fi = ((size_t)(kidx * 3 + mfv) * 64 + lane) * 8;
                            vh.u = *(const uint4*)(vaH + fi);
                            vl.u = *(const uint4*)(vaL + fi);
                            vacc[ci] = __builtin_amdgcn_mfma_f32_16x16x32_f16(vh.h, bh.h, vacc[ci], 0, 0, 0);
                            vacc[ci] = __builtin_amdgcn_mfma_f32_16x16x32_f16(vh.h, bl.h, vacc[ci], 0, 0, 0);
                            vacc[ci] = __builtin_amdgcn_mfma_f32_16x16x32_f16(vl.h, bh.h, vacc[ci], 0, 0, 0);
                        }
                    }
                }
            }
        }
    }

    // main epilogue (unmasked; kZ zeroes inactive channels after kC)
    #pragma unroll
    for (int mfl = 0; mfl < 2; ++mfl) {
        #pragma unroll
        for (int reg = 0; reg < 4; ++reg) {
            const int oc = (wid * 2 + mfl) * 16 + hi4 * 4 + reg;
            float* ob = out + (((size_t)n * OCH + oc) * HH + y0) * WW;
            #pragma unroll
            for (int nf = 0; nf < 4; ++nf) {
                int col = nf * 16 + lcol;
                if (col < WW) ob[col] = acc[mfl][nf][reg];
            }
        }
    }

    // vote epilogue
    __syncthreads();
    float* projT = (float*)smem;                // px*49 + j, max 3134
    int* hist = (int*)&smem[4096];
    {
        const int px = vnf * 16 + lcol;
        if (wid < 4) {
            #pragma unroll
            for (int ci = 0; ci < 2; ++ci)
                #pragma unroll
                for (int reg = 0; reg < 4; ++reg)
                    projT[px * 49 + ci * 16 + hi4 * 4 + reg] = vacc[ci][reg];
        } else {
            #pragma unroll
            for (int reg = 0; reg < 4; ++reg)
                projT[px * 49 + 32 + hi4 * 4 + reg] = vacc[0][reg];
        }
    }
    hist[t] = 0;
    __syncthreads();
    if (t < WW) {
        const int ry = (y0 == 0) ? 0 : ((y0 == HH - 1) ? 2 : 1);
        const int rx = (t == 0) ? 0 : ((t == WW - 1) ? 2 : 1);
        const float* ct = ctab + (ry * 3 + rx) * NB;
        const float* pr = projT + t * 49;
        #pragma unroll
        for (int h = 0; h < NH; ++h) {
            int b = 0;
            #pragma unroll
            for (int bb = 0; bb < BITS_; ++bb)
                if (pr[h * BITS_ + bb] + ct[h * BITS_ + bb] > 0.f) b |= (1 << bb);
            atomicAdd(&hist[h * TS + (b & (TS - 1))], 1);
        }
    }
    __syncthreads();
    {
        int v = hist[t];
        if (v) atomicAdd(&tallied[t], v);
    }
}

// ---------------- kC: argmax, mask, small outputs ----------------
__global__ void kC(const int* __restrict__ tallied, const int* __restrict__ bucket_k,
                   float* __restrict__ o_tallied, float* __restrict__ o_indices,
                   float* __restrict__ o_mask, int* __restrict__ mask_i)
{
    const int t = threadIdx.x;
    __shared__ int s_idx[NH];
    if (t < NH) {
        int best = tallied[t * TS];
        int bi = 0;
        for (int b = 1; b < TS; ++b) {
            int v = tallied[t * TS + b];
            if (v > best) { best = v; bi = b; }
        }
        s_idx[t] = bi;
        o_indices[t] = (float)bi;
    }
    for (int i = t; i < NH * TS; i += 256) o_tallied[i] = (float)tallied[i];
    __syncthreads();
    int mk = 0;
    #pragma unroll
    for (int hp = 0; hp < NH; ++hp) {
        int b = bucket_k[hp * OCH + t];
        #pragma unroll
        for (int h = 0; h < NH; ++h) mk |= (b == s_idx[h]) ? 1 : 0;
    }
    mask_i[t] = mk;
    o_mask[t] = (float)mk;
}

// ---------------- kZ: zero inactive output channels (all 256) ----------------
__global__ void __launch_bounds__(256) kZ(float* __restrict__ out,
                                          const int* __restrict__ mask_i)
{
    const int b = blockIdx.x;
    const int oc = b & (OCH - 1);
    if (mask_i[oc]) return;
    const int n = b >> 8;
    float4* o = (float4*)(out + ((size_t)n * OCH + oc) * HW);
    for (int i = threadIdx.x; i < HW / 4; i += 256)
        o[i] = make_float4(0.f, 0.f, 0.f, 0.f);
}

extern "C" void kernel_launch(void* const* d_in, const int* in_sizes, int n_in,
                              void* d_out, int out_size, void* d_ws, size_t ws_size,
                              hipStream_t stream)
{
    const float* x    = (const float*)d_in[0];
    const float* kern = (const float*)d_in[1];
    const float* a    = (const float*)d_in[2];

    float* out       = (float*)d_out;
    float* o_tallied = out + (size_t)NN * OCH * HW;
    float* o_indices = o_tallied + NH * TS;
    float* o_mask    = o_indices + NH;

    float* ws = (float*)d_ws;
    float* aT       = ws;                      // 24120 -> pad 24320
    float* ctab     = ws + 24320;              // 360 -> pad 384
    float* normP    = ws + 24704;              // 1024
    int*   tallied  = (int*)(ws + 25728);      // 512
    int*   bucket_k = (int*)(ws + 26240);      // 2048
    int*   mask_i   = (int*)(ws + 28288);      // 256
    unsigned short* whA = (unsigned short*)(ws + 28544);    // 73728 f
    unsigned short* vaH = (unsigned short*)(ws + 102272);   // 13824 f
    unsigned short* vaL = (unsigned short*)(ws + 116096);   // 13824 f

    kP<<<123, 256, 0, stream>>>(kern, a, aT, ctab, tallied, normP, whA, vaH, vaL);
    kH<<<OCH, 256, 0, stream>>>(kern, aT, normP, bucket_k);
    kM<<<dim3(HH, NN), dim3(64, 8), 0, stream>>>(x, whA, vaH, vaL, ctab, tallied, out);
    kC<<<1, 256, 0, stream>>>(tallied, bucket_k, o_tallied, o_indices, o_mask, mask_i);
    kZ<<<NN * OCH, 256, 0, stream>>>(out, mask_i);
}

// Round 8
// 139.758 us; speedup vs baseline: 1.1357x; 1.1357x over previous
//
#include <hip/hip_runtime.h>
#include <math.h>

#define NH 8
#define BITS_ 5
#define NB 40
#define TS 64
#define MAUG 27
#define CIN 64
#define HH 56
#define WW 56
#define NN 32
#define OCH 256
#define DK 576
#define DPM 603
#define HW (HH*WW)

#define UST 69             // 16B units per (r,unit) row: 68 used + 1 bank-stagger
#define LO_OFF 6624        // dword offset of lo tile = 3*8*UST*4
#define SMEM_DW 13248      // 2 tiles * 3 rows * 8 units * UST * 4 dw = 51.75 KB

typedef __attribute__((ext_vector_type(4))) float f32x4;
typedef __attribute__((ext_vector_type(8))) _Float16 f16x8;
typedef union { uint4 u; f16x8 h; } fragh_u;

__device__ __forceinline__ unsigned int f16b(float v) {
    union { _Float16 h; unsigned short u; } cv;
    cv.h = (_Float16)v;
    return (unsigned int)cv.u;
}
__device__ __forceinline__ float f16tof(unsigned int b) {
    union { _Float16 h; unsigned short u; } cv;
    cv.u = (unsigned short)b;
    return (float)cv.h;
}

// ---------------- kP: all prep (aT, ctab, zero tallied, norm partials, weight pack) ----
__global__ void kP(const float* __restrict__ kern, const float* __restrict__ a,
                   float* __restrict__ aT, float* __restrict__ ctab,
                   int* __restrict__ tallied, float* __restrict__ normP,
                   unsigned short* __restrict__ whA,
                   unsigned short* __restrict__ vaH, unsigned short* __restrict__ vaL)
{
    const int bid = blockIdx.x;
    const int t = threadIdx.x;
    if (bid < 32) {                       // transpose a -> aT
        for (int idx = bid * 256 + t; idx < DPM * NB; idx += 32 * 256) {
            int d = idx / NB, j = idx - d * NB;
            aT[idx] = a[j * DPM + d];
        }
    } else if (bid == 32) {               // ctab + zero tallied
        for (int g = t; g < 9 * NB; g += 256) {
            int pat = g / NB, j = g - pat * NB;
            int ry = pat / 3, rx = pat % 3;
            float s = 0.f;
            for (int ky = 0; ky < 3; ++ky) {
                if (ry == 0 && ky == 0) continue;
                if (ry == 2 && ky == 2) continue;
                for (int kx = 0; kx < 3; ++kx) {
                    if (rx == 0 && kx == 0) continue;
                    if (rx == 2 && kx == 2) continue;
                    for (int mc = 0; mc < 3; ++mc)
                        s += a[j * DPM + DK + mc * 9 + ky * 3 + kx];
                }
            }
            ctab[g] = 0.5f * s;
        }
        for (int g = t; g < NH * TS; g += 256) tallied[g] = 0;
    } else if (bid < 37) {                // norm partials
        int g = (bid - 33) * 256 + t;     // 1024 = 256 oc * 4 parts
        int oc = g >> 2, part = g & 3;
        const float4* p = (const float4*)(kern + oc * DK + part * 144);
        float sq = 0.f;
        #pragma unroll 4
        for (int i = 0; i < 36; ++i) {
            float4 v = p[i];
            sq += v.x * v.x + v.y * v.y + v.z * v.z + v.w * v.w;
        }
        normP[g] = sq;
    } else {                              // weight packing (342 frags * 64 lanes)
        int idx = (bid - 37) * 256 + t;
        int f = idx >> 6, lane = idx & 63;
        if (f < 288) {                    // main conv: single f16 A-frags
            const int kidxG = f >> 4, mf = f & 15;
            const int tap = kidxG % 9, cc = kidxG / 9;
            const int oc = mf * 16 + (lane & 15);
            const int cbase = cc * 32 + (lane >> 4) * 8;
            unsigned int hs[8];
            #pragma unroll
            for (int j = 0; j < 8; ++j)
                hs[j] = f16b(kern[oc * DK + (cbase + j) * 9 + tap]);
            unsigned int* p = (unsigned int*)(whA + ((size_t)f * 64 + lane) * 8);
            #pragma unroll
            for (int w2 = 0; w2 < 4; ++w2)
                p[w2] = hs[2 * w2] | (hs[2 * w2 + 1] << 16);
        } else if (f < 342) {             // vote: f16 hi/lo A-frags
            const int fv = f - 288;
            const int kidxG = fv / 3, mfv = fv % 3;
            const int tap = kidxG % 9, cc = kidxG / 9;
            const int j = mfv * 16 + (lane & 15);
            const int cbase = cc * 32 + (lane >> 4) * 8;
            unsigned int hs[8], ls[8];
            #pragma unroll
            for (int jj = 0; jj < 8; ++jj) {
                float w = (j < NB) ? a[j * DPM + (cbase + jj) * 9 + tap] : 0.f;
                unsigned int h = f16b(w);
                unsigned int l = f16b(w - f16tof(h));
                hs[jj] = h; ls[jj] = l;
            }
            unsigned int* ph = (unsigned int*)(vaH + ((size_t)fv * 64 + lane) * 8);
            unsigned int* pl = (unsigned int*)(vaL + ((size_t)fv * 64 + lane) * 8);
            #pragma unroll
            for (int w2 = 0; w2 < 4; ++w2) {
                ph[w2] = hs[2 * w2] | (hs[2 * w2 + 1] << 16);
                pl[w2] = ls[2 * w2] | (ls[2 * w2 + 1] << 16);
            }
        }
    }
}

// ---------------- kH: hash kernel vectors, one block per oc -------------------------
__global__ void __launch_bounds__(256) kH(const float* __restrict__ kern,
        const float* __restrict__ aT, const float* __restrict__ normP,
        int* __restrict__ bucket_k)
{
    __shared__ float xs[DK];
    __shared__ float red[256];
    __shared__ float accR[3 * 41];
    __shared__ float proj[NB];
    const int t = threadIdx.x;
    const int lane = t & 63, ty = t >> 6;
    const int oc = blockIdx.x;

    red[t] = fmaxf(fmaxf(normP[t], normP[t + 256]), fmaxf(normP[t + 512], normP[t + 768]));
    __syncthreads();
    for (int s = 128; s > 0; s >>= 1) {
        if (t < s) red[t] = fmaxf(red[t], red[t + s]);
        __syncthreads();
    }
    const float scale = 0.83f / sqrtf(red[0]);
    for (int i = t; i < DK; i += 256) xs[i] = scale * kern[(size_t)oc * DK + i];
    __syncthreads();

    const int j = (lane < NB) ? lane : (NB - 1);
    float acc = 0.f, sq = 0.f;
    const int d0 = ty * 144;
    for (int d = d0; d < d0 + 144; ++d) {
        float xv = xs[d];
        sq += xv * xv;
        acc += xv * aT[d * NB + j];
    }
    if (ty > 0) {
        if (lane < NB) accR[(ty - 1) * 41 + lane] = acc;
        if (lane == NB) accR[(ty - 1) * 41 + 40] = sq;
    }
    __syncthreads();
    if (ty == 0 && lane < NB) {
        acc += (accR[lane] + accR[41 + lane]) + accR[82 + lane];
        sq += (accR[40] + accR[81]) + accR[122];
        float pv = sq;
        for (int m = 0; m < MAUG; ++m) {
            acc += pv * aT[(DK + m) * NB + lane];
            pv = pv * pv;
        }
        proj[lane] = acc;
    }
    __syncthreads();
    if (t < NH) {
        int b = 0;
        #pragma unroll
        for (int bb = 0; bb < BITS_; ++bb)
            if (proj[t * BITS_ + bb] > 0.f) b |= (1 << bb);
        bucket_k[t * OCH + oc] = b & (TS - 1);
    }
}

// ---------------- kM: single-pass 256-oc main conv + vote, M=64/wave ------------------
// grid (56, NN), block 256 (4 waves). 1 output row; 3 x-rows x 64 ch staged (hi+lo f16).
// Wave mg owns oc [mg*64, mg*64+64) (acc[4][4]) and vote px-group mg (all 3 mfv).
__global__ void __launch_bounds__(256, 3) kM(const float* __restrict__ x,
        const unsigned short* __restrict__ whA,
        const unsigned short* __restrict__ vaH, const unsigned short* __restrict__ vaL,
        const float* __restrict__ ctab, int* __restrict__ tallied,
        float* __restrict__ out)
{
    __shared__ unsigned int smem[SMEM_DW];
    const int t = threadIdx.x;
    const int lane = t & 63, wid = t >> 6;
    const int y0 = blockIdx.x, n = blockIdx.y;
    const int lcol = lane & 15, hi4 = lane >> 4;
    const int mg = wid;

    f32x4 acc[4][4];
    #pragma unroll
    for (int mf = 0; mf < 4; ++mf)
        #pragma unroll
        for (int nf = 0; nf < 4; ++nf)
            acc[mf][nf] = (f32x4){0.f, 0.f, 0.f, 0.f};
    f32x4 vacc[3];
    vacc[0] = (f32x4){0.f, 0.f, 0.f, 0.f};
    vacc[1] = (f32x4){0.f, 0.f, 0.f, 0.f};
    vacc[2] = (f32x4){0.f, 0.f, 0.f, 0.f};

    // zero pad units: L=0 and L=57..68 per (tile, r, unit)
    for (int i = t; i < 624; i += 256) {
        int li = i % 13;
        int rem = i / 13;
        int L = (li == 0) ? 0 : 56 + li;
        int unit = rem & 7, r = (rem >> 3) % 3, tile = rem / 24;
        *(uint4*)&smem[((tile * 24 + r * 8 + unit) * UST + L) * 4] =
            make_uint4(0u, 0u, 0u, 0u);
    }

    // stage 3 rows x 64 ch (hi + lo f16); thread: col=lane, 16-ch group g=wid
    {
        const int col = lane;
        const int g = wid;
        #pragma unroll
        for (int r = 0; r < 3; ++r) {
            const int y = y0 - 1 + r;
            const bool valid = (col < WW) && (y >= 0) && (y < HH);
            const float* xb = x + (((size_t)n * CIN + g * 16) * HH + (valid ? y : 0)) * WW + col;
            #pragma unroll
            for (int uu = 0; uu < 2; ++uu) {
                unsigned int dh[4], dl[4];
                #pragma unroll
                for (int dd = 0; dd < 4; ++dd) {
                    float v0 = valid ? xb[(size_t)(uu * 8 + dd * 2) * HW] : 0.f;
                    float v1 = valid ? xb[(size_t)(uu * 8 + dd * 2 + 1) * HW] : 0.f;
                    unsigned int h0 = f16b(v0), h1 = f16b(v1);
                    unsigned int l0 = f16b(v0 - f16tof(h0));
                    unsigned int l1 = f16b(v1 - f16tof(h1));
                    dh[dd] = h0 | (h1 << 16);
                    dl[dd] = l0 | (l1 << 16);
                }
                if (col < WW) {
                    const int unit = g * 2 + uu;
                    const int ad = ((r * 8 + unit) * UST + 1 + col) * 4;
                    *(uint4*)&smem[ad] = make_uint4(dh[0], dh[1], dh[2], dh[3]);
                    *(uint4*)&smem[LO_OFF + ad] = make_uint4(dl[0], dl[1], dl[2], dl[3]);
                }
            }
        }
    }
    __syncthreads();

    // K-loop: kidx = cc*9 + tap ascending (order matches prior passing rounds)
    for (int cc = 0; cc < 2; ++cc) {
        #pragma unroll
        for (int tap = 0; tap < 9; ++tap) {
            const int kidx = cc * 9 + tap;
            const int ky = tap / 3, kx = tap - ky * 3;
            fragh_u ah[4];
            #pragma unroll
            for (int mf = 0; mf < 4; ++mf)
                ah[mf].u = *(const uint4*)(whA + (((size_t)kidx * 16 + mg * 4 + mf) * 64 + lane) * 8);
            #pragma unroll
            for (int nf = 0; nf < 4; ++nf) {
                const int ad = ((ky * 8 + cc * 4 + hi4) * UST + nf * 16 + lcol + kx) * 4;
                fragh_u bh;
                bh.u = *(const uint4*)&smem[ad];
                acc[0][nf] = __builtin_amdgcn_mfma_f32_16x16x32_f16(ah[0].h, bh.h, acc[0][nf], 0, 0, 0);
                acc[1][nf] = __builtin_amdgcn_mfma_f32_16x16x32_f16(ah[1].h, bh.h, acc[1][nf], 0, 0, 0);
                acc[2][nf] = __builtin_amdgcn_mfma_f32_16x16x32_f16(ah[2].h, bh.h, acc[2][nf], 0, 0, 0);
                acc[3][nf] = __builtin_amdgcn_mfma_f32_16x16x32_f16(ah[3].h, bh.h, acc[3][nf], 0, 0, 0);
                if (nf == mg) {
                    fragh_u bl;
                    bl.u = *(const uint4*)&smem[LO_OFF + ad];
                    #pragma unroll
                    for (int mfv = 0; mfv < 3; ++mfv) {
                        fragh_u vh, vl;
                        size_t fi = ((size_t)(kidx * 3 + mfv) * 64 + lane) * 8;
                        vh.u = *(const uint4*)(vaH + fi);
                        vl.u = *(const uint4*)(vaL + fi);
                        vacc[mfv] = __builtin_amdgcn_mfma_f32_16x16x32_f16(vh.h, bh.h, vacc[mfv], 0, 0, 0);
                        vacc[mfv] = __builtin_amdgcn_mfma_f32_16x16x32_f16(vh.h, bl.h, vacc[mfv], 0, 0, 0);
                        vacc[mfv] = __builtin_amdgcn_mfma_f32_16x16x32_f16(vl.h, bh.h, vacc[mfv], 0, 0, 0);
                    }
                }
            }
        }
    }

    // main epilogue (unmasked; kZ zeroes inactive channels after kC)
    #pragma unroll
    for (int mf = 0; mf < 4; ++mf) {
        #pragma unroll
        for (int reg = 0; reg < 4; ++reg) {
            const int oc = (mg * 4 + mf) * 16 + hi4 * 4 + reg;
            float* ob = out + (((size_t)n * OCH + oc) * HH + y0) * WW;
            #pragma unroll
            for (int nf = 0; nf < 4; ++nf) {
                int col = nf * 16 + lcol;
                if (col < WW) ob[col] = acc[mf][nf][reg];
            }
        }
    }

    // vote epilogue
    __syncthreads();
    float* projT = (float*)smem;            // px*49 + j  (<= 3136 floats)
    int* hist = (int*)&smem[4096];
    {
        const int px = mg * 16 + lcol;
        #pragma unroll
        for (int mfv = 0; mfv < 3; ++mfv)
            #pragma unroll
            for (int reg = 0; reg < 4; ++reg)
                projT[px * 49 + mfv * 16 + hi4 * 4 + reg] = vacc[mfv][reg];
    }
    hist[t] = 0;
    hist[t + 256] = 0;
    __syncthreads();
    if (t < WW) {
        const int ry = (y0 == 0) ? 0 : ((y0 == HH - 1) ? 2 : 1);
        const int rx = (t == 0) ? 0 : ((t == WW - 1) ? 2 : 1);
        const float* ct = ctab + (ry * 3 + rx) * NB;
        const float* pr = projT + t * 49;
        #pragma unroll
        for (int h = 0; h < NH; ++h) {
            int b = 0;
            #pragma unroll
            for (int bb = 0; bb < BITS_; ++bb)
                if (pr[h * BITS_ + bb] + ct[h * BITS_ + bb] > 0.f) b |= (1 << bb);
            atomicAdd(&hist[h * TS + (b & (TS - 1))], 1);
        }
    }
    __syncthreads();
    {
        int v = hist[t];
        if (v) atomicAdd(&tallied[t], v);
        v = hist[t + 256];
        if (v) atomicAdd(&tallied[t + 256], v);
    }
}

// ---------------- kC: argmax, mask, small outputs ----------------
__global__ void kC(const int* __restrict__ tallied, const int* __restrict__ bucket_k,
                   float* __restrict__ o_tallied, float* __restrict__ o_indices,
                   float* __restrict__ o_mask, int* __restrict__ mask_i)
{
    const int t = threadIdx.x;
    __shared__ int s_idx[NH];
    if (t < NH) {
        int best = tallied[t * TS];
        int bi = 0;
        for (int b = 1; b < TS; ++b) {
            int v = tallied[t * TS + b];
            if (v > best) { best = v; bi = b; }
        }
        s_idx[t] = bi;
        o_indices[t] = (float)bi;
    }
    for (int i = t; i < NH * TS; i += 256) o_tallied[i] = (float)tallied[i];
    __syncthreads();
    int mk = 0;
    #pragma unroll
    for (int hp = 0; hp < NH; ++hp) {
        int b = bucket_k[hp * OCH + t];
        #pragma unroll
        for (int h = 0; h < NH; ++h) mk |= (b == s_idx[h]) ? 1 : 0;
    }
    mask_i[t] = mk;
    o_mask[t] = (float)mk;
}

// ---------------- kZ: zero inactive output channels (all 256) ----------------
__global__ void __launch_bounds__(256) kZ(float* __restrict__ out,
                                          const int* __restrict__ mask_i)
{
    const int b = blockIdx.x;
    const int oc = b & (OCH - 1);
    if (mask_i[oc]) return;
    const int n = b >> 8;
    float4* o = (float4*)(out + ((size_t)n * OCH + oc) * HW);
    for (int i = threadIdx.x; i < HW / 4; i += 256)
        o[i] = make_float4(0.f, 0.f, 0.f, 0.f);
}

extern "C" void kernel_launch(void* const* d_in, const int* in_sizes, int n_in,
                              void* d_out, int out_size, void* d_ws, size_t ws_size,
                              hipStream_t stream)
{
    const float* x    = (const float*)d_in[0];
    const float* kern = (const float*)d_in[1];
    const float* a    = (const float*)d_in[2];

    float* out       = (float*)d_out;
    float* o_tallied = out + (size_t)NN * OCH * HW;
    float* o_indices = o_tallied + NH * TS;
    float* o_mask    = o_indices + NH;

    float* ws = (float*)d_ws;
    float* aT       = ws;                      // 24120 -> pad 24320
    float* ctab     = ws + 24320;              // 360 -> pad 384
    float* normP    = ws + 24704;              // 1024
    int*   tallied  = (int*)(ws + 25728);      // 512
    int*   bucket_k = (int*)(ws + 26240);      // 2048
    int*   mask_i   = (int*)(ws + 28288);      // 256
    unsigned short* whA = (unsigned short*)(ws + 28544);    // 73728 f
    unsigned short* vaH = (unsigned short*)(ws + 102272);   // 13824 f
    unsigned short* vaL = (unsigned short*)(ws + 116096);   // 13824 f

    kP<<<123, 256, 0, stream>>>(kern, a, aT, ctab, tallied, normP, whA, vaH, vaL);
    kH<<<OCH, 256, 0, stream>>>(kern, aT, normP, bucket_k);
    kM<<<dim3(HH, NN), 256, 0, stream>>>(x, whA, vaH, vaL, ctab, tallied, out);
    kC<<<1, 256, 0, stream>>>(tallied, bucket_k, o_tallied, o_indices, o_mask, mask_i);
    kZ<<<NN * OCH, 256, 0, stream>>>(out, mask_i);
}

// Round 9
// 112.422 us; speedup vs baseline: 1.4119x; 1.2432x over previous
//
#include <hip/hip_runtime.h>
#include <math.h>

#define NH 8
#define BITS_ 5
#define NB 40
#define TS 64
#define MAUG 27
#define CIN 64
#define HH 56
#define WW 56
#define NN 32
#define OCH 256
#define DK 576
#define DPM 603
#define HW (HH*WW)

#define UST 59             // 16B cells per (r,unit) row: L=0 pad, 1..56 data, 57 pad, 58 stagger
#define LO_OFF 7552        // dword offset of lo tile = 4*8*UST*4
#define SMEM_DW 15104      // 2 tiles * 4 rows * 8 units * UST * 4 dw = 60.4 KB

typedef __attribute__((ext_vector_type(4))) float f32x4;
typedef __attribute__((ext_vector_type(8))) _Float16 f16x8;
typedef union { uint4 u; f16x8 h; } fragh_u;

__device__ __forceinline__ unsigned int f16b(float v) {
    union { _Float16 h; unsigned short u; } cv;
    cv.h = (_Float16)v;
    return (unsigned int)cv.u;
}
__device__ __forceinline__ float f16tof(unsigned int b) {
    union { _Float16 h; unsigned short u; } cv;
    cv.u = (unsigned short)b;
    return (float)cv.h;
}

// ---------------- kP: all prep (aT, ctab, zero tallied, norm partials, weight pack) ----
__global__ void kP(const float* __restrict__ kern, const float* __restrict__ a,
                   float* __restrict__ aT, float* __restrict__ ctab,
                   int* __restrict__ tallied, float* __restrict__ normP,
                   unsigned short* __restrict__ whA,
                   unsigned short* __restrict__ vaH, unsigned short* __restrict__ vaL)
{
    const int bid = blockIdx.x;
    const int t = threadIdx.x;
    if (bid < 32) {                       // transpose a -> aT
        for (int idx = bid * 256 + t; idx < DPM * NB; idx += 32 * 256) {
            int d = idx / NB, j = idx - d * NB;
            aT[idx] = a[j * DPM + d];
        }
    } else if (bid == 32) {               // ctab + zero tallied
        for (int g = t; g < 9 * NB; g += 256) {
            int pat = g / NB, j = g - pat * NB;
            int ry = pat / 3, rx = pat % 3;
            float s = 0.f;
            for (int ky = 0; ky < 3; ++ky) {
                if (ry == 0 && ky == 0) continue;
                if (ry == 2 && ky == 2) continue;
                for (int kx = 0; kx < 3; ++kx) {
                    if (rx == 0 && kx == 0) continue;
                    if (rx == 2 && kx == 2) continue;
                    for (int mc = 0; mc < 3; ++mc)
                        s += a[j * DPM + DK + mc * 9 + ky * 3 + kx];
                }
            }
            ctab[g] = 0.5f * s;
        }
        for (int g = t; g < NH * TS; g += 256) tallied[g] = 0;
    } else if (bid < 37) {                // norm partials
        int g = (bid - 33) * 256 + t;     // 1024 = 256 oc * 4 parts
        int oc = g >> 2, part = g & 3;
        const float4* p = (const float4*)(kern + oc * DK + part * 144);
        float sq = 0.f;
        #pragma unroll 4
        for (int i = 0; i < 36; ++i) {
            float4 v = p[i];
            sq += v.x * v.x + v.y * v.y + v.z * v.z + v.w * v.w;
        }
        normP[g] = sq;
    } else {                              // weight packing (342 frags * 64 lanes)
        int idx = (bid - 37) * 256 + t;
        int f = idx >> 6, lane = idx & 63;
        if (f < 288) {                    // main conv: single f16 A-frags
            const int kidxG = f >> 4, mf = f & 15;
            const int tap = kidxG % 9, cc = kidxG / 9;
            const int oc = mf * 16 + (lane & 15);
            const int cbase = cc * 32 + (lane >> 4) * 8;
            unsigned int hs[8];
            #pragma unroll
            for (int j = 0; j < 8; ++j)
                hs[j] = f16b(kern[oc * DK + (cbase + j) * 9 + tap]);
            unsigned int* p = (unsigned int*)(whA + ((size_t)f * 64 + lane) * 8);
            #pragma unroll
            for (int w2 = 0; w2 < 4; ++w2)
                p[w2] = hs[2 * w2] | (hs[2 * w2 + 1] << 16);
        } else if (f < 342) {             // vote: f16 hi/lo A-frags
            const int fv = f - 288;
            const int kidxG = fv / 3, mfv = fv % 3;
            const int tap = kidxG % 9, cc = kidxG / 9;
            const int j = mfv * 16 + (lane & 15);
            const int cbase = cc * 32 + (lane >> 4) * 8;
            unsigned int hs[8], ls[8];
            #pragma unroll
            for (int jj = 0; jj < 8; ++jj) {
                float w = (j < NB) ? a[j * DPM + (cbase + jj) * 9 + tap] : 0.f;
                unsigned int h = f16b(w);
                unsigned int l = f16b(w - f16tof(h));
                hs[jj] = h; ls[jj] = l;
            }
            unsigned int* ph = (unsigned int*)(vaH + ((size_t)fv * 64 + lane) * 8);
            unsigned int* pl = (unsigned int*)(vaL + ((size_t)fv * 64 + lane) * 8);
            #pragma unroll
            for (int w2 = 0; w2 < 4; ++w2) {
                ph[w2] = hs[2 * w2] | (hs[2 * w2 + 1] << 16);
                pl[w2] = ls[2 * w2] | (ls[2 * w2 + 1] << 16);
            }
        }
    }
}

// ---------------- kH: hash kernel vectors, one block per oc -------------------------
__global__ void __launch_bounds__(256) kH(const float* __restrict__ kern,
        const float* __restrict__ aT, const float* __restrict__ normP,
        int* __restrict__ bucket_k)
{
    __shared__ float xs[DK];
    __shared__ float red[256];
    __shared__ float accR[3 * 41];
    __shared__ float proj[NB];
    const int t = threadIdx.x;
    const int lane = t & 63, ty = t >> 6;
    const int oc = blockIdx.x;

    red[t] = fmaxf(fmaxf(normP[t], normP[t + 256]), fmaxf(normP[t + 512], normP[t + 768]));
    __syncthreads();
    for (int s = 128; s > 0; s >>= 1) {
        if (t < s) red[t] = fmaxf(red[t], red[t + s]);
        __syncthreads();
    }
    const float scale = 0.83f / sqrtf(red[0]);
    for (int i = t; i < DK; i += 256) xs[i] = scale * kern[(size_t)oc * DK + i];
    __syncthreads();

    const int j = (lane < NB) ? lane : (NB - 1);
    float acc = 0.f, sq = 0.f;
    const int d0 = ty * 144;
    for (int d = d0; d < d0 + 144; ++d) {
        float xv = xs[d];
        sq += xv * xv;
        acc += xv * aT[d * NB + j];
    }
    if (ty > 0) {
        if (lane < NB) accR[(ty - 1) * 41 + lane] = acc;
        if (lane == NB) accR[(ty - 1) * 41 + 40] = sq;
    }
    __syncthreads();
    if (ty == 0 && lane < NB) {
        acc += (accR[lane] + accR[41 + lane]) + accR[82 + lane];
        sq += (accR[40] + accR[81]) + accR[122];
        float pv = sq;
        for (int m = 0; m < MAUG; ++m) {
            acc += pv * aT[(DK + m) * NB + lane];
            pv = pv * pv;
        }
        proj[lane] = acc;
    }
    __syncthreads();
    if (t < NH) {
        int b = 0;
        #pragma unroll
        for (int bb = 0; bb < BITS_; ++bb)
            if (proj[t * BITS_ + bb] > 0.f) b |= (1 << bb);
        bucket_k[t * OCH + oc] = b & (TS - 1);
    }
}

// ---------------- kM: single-pass 256-oc conv + vote, 8 waves, 2 rows -----------------
// grid (28, NN), block (64,8). Wave (mg=wid&3, ng=wid>>2): M=64 oc, N: overlapping
// n-tiles at col bases {0,16,32,40} (cols 40..47 double-computed identically).
__global__ void __launch_bounds__(512, 4) kM(const float* __restrict__ x,
        const unsigned short* __restrict__ whA,
        const unsigned short* __restrict__ vaH, const unsigned short* __restrict__ vaL,
        const float* __restrict__ ctab, int* __restrict__ tallied,
        float* __restrict__ out)
{
    __shared__ unsigned int smem[SMEM_DW];
    const int lane = threadIdx.x, wid = threadIdx.y;
    const int y0 = blockIdx.x * 2, n = blockIdx.y;
    const int lcol = lane & 15, hi4 = lane >> 4;
    const int t = wid * 64 + lane;
    const int mg = wid & 3, ng = wid >> 2;
    const int colbase = (mg == 3) ? 40 : mg * 16;

    f32x4 acc[4][4];
    #pragma unroll
    for (int mf = 0; mf < 4; ++mf)
        #pragma unroll
        for (int nf = 0; nf < 4; ++nf)
            acc[mf][nf] = (f32x4){0.f, 0.f, 0.f, 0.f};
    f32x4 vacc[3];
    vacc[0] = (f32x4){0.f, 0.f, 0.f, 0.f};
    vacc[1] = (f32x4){0.f, 0.f, 0.f, 0.f};
    vacc[2] = (f32x4){0.f, 0.f, 0.f, 0.f};

    // zero pad cells: L=0 and L=57 for 4 rows x 8 units x 2 tiles
    if (t < 256) {
        const int tile = t >> 7, rem = t & 127;
        const int L = (rem & 1) ? 57 : 0;
        const int u = (rem >> 1) & 7, r = rem >> 4;
        *(uint4*)&smem[tile * LO_OFF + ((r * 8 + u) * UST + L) * 4] =
            make_uint4(0u, 0u, 0u, 0u);
    }

    // stage: wave (r=wid&3, half=wid>>2), thread col=lane; 4 units (32 ch), hi+lo
    {
        const int r = wid & 3, half = wid >> 2;
        const int y = y0 - 1 + r;
        const bool valid = (lane < WW) && (y >= 0) && (y < HH);
        const float* xb = x + (((size_t)n * CIN + half * 32) * HH + (valid ? y : 0)) * WW + lane;
        #pragma unroll
        for (int uu = 0; uu < 4; ++uu) {
            unsigned int dh[4], dl[4];
            #pragma unroll
            for (int dd = 0; dd < 4; ++dd) {
                float v0 = valid ? xb[(size_t)(uu * 8 + dd * 2) * HW] : 0.f;
                float v1 = valid ? xb[(size_t)(uu * 8 + dd * 2 + 1) * HW] : 0.f;
                unsigned int h0 = f16b(v0), h1 = f16b(v1);
                unsigned int l0 = f16b(v0 - f16tof(h0));
                unsigned int l1 = f16b(v1 - f16tof(h1));
                dh[dd] = h0 | (h1 << 16);
                dl[dd] = l0 | (l1 << 16);
            }
            if (valid || (lane < WW)) {
                const int ad = ((r * 8 + half * 4 + uu) * UST + 1 + lane) * 4;
                *(uint4*)&smem[ad] = make_uint4(dh[0], dh[1], dh[2], dh[3]);
                *(uint4*)&smem[LO_OFF + ad] = make_uint4(dl[0], dl[1], dl[2], dl[3]);
            }
        }
    }
    __syncthreads();

    // K-loop, fully unrolled; kidx = cc*9+tap ascending (order as prior passing rounds)
    const uint4* wbase = (const uint4*)whA + (size_t)mg * 4 * 64 + lane;
    const uint4* vbaseH = (const uint4*)vaH + lane;
    const uint4* vbaseL = (const uint4*)vaL + lane;
    const int rowu = (ng * 8 + hi4) * UST + lcol;
    #pragma unroll
    for (int kidx = 0; kidx < 18; ++kidx) {
        const int cc = kidx / 9, tap = kidx % 9;
        const int ky = tap / 3, kx = tap % 3;
        fragh_u ah[4];
        #pragma unroll
        for (int mf = 0; mf < 4; ++mf)
            ah[mf].u = wbase[kidx * 1024 + mf * 64];
        #pragma unroll
        for (int nf = 0; nf < 4; ++nf) {
            const int nb = (nf == 3) ? 40 : nf * 16;
            const int ad = (rowu + (ky * 8 + cc * 4) * UST + nb + kx) * 4;
            fragh_u bh;
            bh.u = *(const uint4*)&smem[ad];
            acc[0][nf] = __builtin_amdgcn_mfma_f32_16x16x32_f16(ah[0].h, bh.h, acc[0][nf], 0, 0, 0);
            acc[1][nf] = __builtin_amdgcn_mfma_f32_16x16x32_f16(ah[1].h, bh.h, acc[1][nf], 0, 0, 0);
            acc[2][nf] = __builtin_amdgcn_mfma_f32_16x16x32_f16(ah[2].h, bh.h, acc[2][nf], 0, 0, 0);
            acc[3][nf] = __builtin_amdgcn_mfma_f32_16x16x32_f16(ah[3].h, bh.h, acc[3][nf], 0, 0, 0);
            if (nf == mg) {
                fragh_u bl;
                bl.u = *(const uint4*)&smem[LO_OFF + ad];
                #pragma unroll
                for (int mfv = 0; mfv < 3; ++mfv) {
                    fragh_u vh, vl;
                    vh.u = vbaseH[(kidx * 3 + mfv) * 64];
                    vl.u = vbaseL[(kidx * 3 + mfv) * 64];
                    vacc[mfv] = __builtin_amdgcn_mfma_f32_16x16x32_f16(vh.h, bh.h, vacc[mfv], 0, 0, 0);
                    vacc[mfv] = __builtin_amdgcn_mfma_f32_16x16x32_f16(vh.h, bl.h, vacc[mfv], 0, 0, 0);
                    vacc[mfv] = __builtin_amdgcn_mfma_f32_16x16x32_f16(vl.h, bh.h, vacc[mfv], 0, 0, 0);
                }
            }
        }
    }

    // main epilogue (unmasked; kZ zeroes inactive channels after kC). cols always < 56.
    const int yrow = y0 + ng;
    #pragma unroll
    for (int mf = 0; mf < 4; ++mf) {
        #pragma unroll
        for (int reg = 0; reg < 4; ++reg) {
            const int oc = (mg * 4 + mf) * 16 + hi4 * 4 + reg;
            float* ob = out + (((size_t)n * OCH + oc) * HH + yrow) * WW;
            #pragma unroll
            for (int nf = 0; nf < 4; ++nf) {
                const int col = ((nf == 3) ? 40 : nf * 16) + lcol;
                ob[col] = acc[mf][nf][reg];
            }
        }
    }

    // vote epilogue (overlap px 40..47 double-written with identical values)
    __syncthreads();
    float* projT = (float*)smem;            // (row*64+px)*49 + j, max 5878 dw
    int* hist = (int*)&smem[6144];
    {
        const int px = colbase + lcol;
        #pragma unroll
        for (int mfv = 0; mfv < 3; ++mfv)
            #pragma unroll
            for (int reg = 0; reg < 4; ++reg)
                projT[(ng * 64 + px) * 49 + mfv * 16 + hi4 * 4 + reg] = vacc[mfv][reg];
    }
    hist[t] = 0;
    __syncthreads();
    if (t < 2 * WW) {
        const int row = t / WW, pxx = t - row * WW;
        const int yv = y0 + row;
        const int ry = (yv == 0) ? 0 : ((yv == HH - 1) ? 2 : 1);
        const int rx = (pxx == 0) ? 0 : ((pxx == WW - 1) ? 2 : 1);
        const float* ct = ctab + (ry * 3 + rx) * NB;
        const float* pr = projT + (row * 64 + pxx) * 49;
        #pragma unroll
        for (int h = 0; h < NH; ++h) {
            int b = 0;
            #pragma unroll
            for (int bb = 0; bb < BITS_; ++bb)
                if (pr[h * BITS_ + bb] + ct[h * BITS_ + bb] > 0.f) b |= (1 << bb);
            atomicAdd(&hist[h * TS + (b & (TS - 1))], 1);
        }
    }
    __syncthreads();
    {
        int v = hist[t];
        if (v) atomicAdd(&tallied[t], v);
    }
}

// ---------------- kC: argmax, mask, small outputs ----------------
__global__ void kC(const int* __restrict__ tallied, const int* __restrict__ bucket_k,
                   float* __restrict__ o_tallied, float* __restrict__ o_indices,
                   float* __restrict__ o_mask, int* __restrict__ mask_i)
{
    const int t = threadIdx.x;
    __shared__ int s_idx[NH];
    if (t < NH) {
        int best = tallied[t * TS];
        int bi = 0;
        for (int b = 1; b < TS; ++b) {
            int v = tallied[t * TS + b];
            if (v > best) { best = v; bi = b; }
        }
        s_idx[t] = bi;
        o_indices[t] = (float)bi;
    }
    for (int i = t; i < NH * TS; i += 256) o_tallied[i] = (float)tallied[i];
    __syncthreads();
    int mk = 0;
    #pragma unroll
    for (int hp = 0; hp < NH; ++hp) {
        int b = bucket_k[hp * OCH + t];
        #pragma unroll
        for (int h = 0; h < NH; ++h) mk |= (b == s_idx[h]) ? 1 : 0;
    }
    mask_i[t] = mk;
    o_mask[t] = (float)mk;
}

// ---------------- kZ: zero inactive output channels (all 256) ----------------
__global__ void __launch_bounds__(256) kZ(float* __restrict__ out,
                                          const int* __restrict__ mask_i)
{
    const int b = blockIdx.x;
    const int oc = b & (OCH - 1);
    if (mask_i[oc]) return;
    const int n = b >> 8;
    float4* o = (float4*)(out + ((size_t)n * OCH + oc) * HW);
    for (int i = threadIdx.x; i < HW / 4; i += 256)
        o[i] = make_float4(0.f, 0.f, 0.f, 0.f);
}

extern "C" void kernel_launch(void* const* d_in, const int* in_sizes, int n_in,
                              void* d_out, int out_size, void* d_ws, size_t ws_size,
                              hipStream_t stream)
{
    const float* x    = (const float*)d_in[0];
    const float* kern = (const float*)d_in[1];
    const float* a    = (const float*)d_in[2];

    float* out       = (float*)d_out;
    float* o_tallied = out + (size_t)NN * OCH * HW;
    float* o_indices = o_tallied + NH * TS;
    float* o_mask    = o_indices + NH;

    float* ws = (float*)d_ws;
    float* aT       = ws;                      // 24120 -> pad 24320
    float* ctab     = ws + 24320;              // 360 -> pad 384
    float* normP    = ws + 24704;              // 1024
    int*   tallied  = (int*)(ws + 25728);      // 512
    int*   bucket_k = (int*)(ws + 26240);      // 2048
    int*   mask_i   = (int*)(ws + 28288);      // 256
    unsigned short* whA = (unsigned short*)(ws + 28544);    // 73728 f
    unsigned short* vaH = (unsigned short*)(ws + 102272);   // 13824 f
    unsigned short* vaL = (unsigned short*)(ws + 116096);   // 13824 f

    kP<<<123, 256, 0, stream>>>(kern, a, aT, ctab, tallied, normP, whA, vaH, vaL);
    kH<<<OCH, 256, 0, stream>>>(kern, aT, normP, bucket_k);
    kM<<<dim3(28, NN), dim3(64, 8), 0, stream>>>(x, whA, vaH, vaL, ctab, tallied, out);
    kC<<<1, 256, 0, stream>>>(tallied, bucket_k, o_tallied, o_indices, o_mask, mask_i);
    kZ<<<NN * OCH, 256, 0, stream>>>(out, mask_i);
}